// Round 13
// baseline (127.036 us; speedup 1.0000x reference)
//
#include <hip/hip_runtime.h>
#include <hip/hip_fp16.h>
#include <cstdint>
#include <cstddef>

// FastGRNN cell, MI355X fp16-MFMA, v13.
// prep:   weights f32->f16 into wb.
// stage1: 256 blocks x 512 thr. x: 128 blocks BM=128 (MI=2); h: 128 blocks
//         BM=256 (MI=4), kp x ncol split. A loads NON-TEMPORAL (L1 bypass,
//         stream-once data) with 2-deep E/O register prefetch; B via
//         global_load_lds(16B, pre-swizzled source). One barrier/iter with
//         COUNTED vmcnt (A(t+2) stays in flight across the barrier).
// stage2: R8-proven form (~21us): plain __syncthreads 1-deep, uh panel add in
//         staging, nt state load / nt out store. pre = [wx|uh0+uh1]@[W2|U2]^T.

typedef _Float16 half8 __attribute__((ext_vector_type(8)));
typedef float f32x4 __attribute__((ext_vector_type(4)));

#define DIN 1024
#define DH 2048
#define RK 256
#define RBLD 768
// wb half-offsets
#define OFF_W1H 0
#define OFF_U1H 262144
#define OFF_W2H 786432
#define OFF_U2H 1310720

__device__ __forceinline__ half8 cvt8(f32x4 a, f32x4 b) {
  half8 h;
  h[0] = (_Float16)a[0]; h[1] = (_Float16)a[1]; h[2] = (_Float16)a[2]; h[3] = (_Float16)a[3];
  h[4] = (_Float16)b[0]; h[5] = (_Float16)b[1]; h[6] = (_Float16)b[2]; h[7] = (_Float16)b[3];
  return h;
}

// 16B global->LDS direct copy. LDS dest is wave-uniform base + lane*16.
__device__ __forceinline__ void gload16(const _Float16* g, _Float16* lds) {
  __builtin_amdgcn_global_load_lds(
      (const __attribute__((address_space(1))) unsigned*)g,
      (__attribute__((address_space(3))) unsigned*)lds, 16, 0, 0);
}

// ---------------- prep: weights f32 -> f16 ----------------------------------
__global__ __launch_bounds__(256)
void fgrnn_prep(const float* __restrict__ W1, const float* __restrict__ U1,
                const float* __restrict__ W2, const float* __restrict__ U2,
                _Float16* __restrict__ wb) {
  const int q = blockIdx.x * 256 + threadIdx.x;
  const float* src;
  int rel;
  if (q < 65536) { src = W1; rel = q; }
  else if (q < 196608) { src = U1; rel = q - 65536; }
  else if (q < 327680) { src = W2; rel = q - 196608; }
  else { src = U2; rel = q - 327680; }
  const float4 v = reinterpret_cast<const float4*>(src)[rel];
  union { _Float16 h[4]; uint2 u; } cv;
  cv.h[0] = (_Float16)v.x; cv.h[1] = (_Float16)v.y;
  cv.h[2] = (_Float16)v.z; cv.h[3] = (_Float16)v.w;
  reinterpret_cast<uint2*>(wb)[q] = cv.u;
}

// ---------------- stage 1 body: BM=64*MI, BN=128, K=1024, 16 iters ----------
// 512 thr = 8 waves (4 x 2); wave tile (MI*16)x64 (acc[MI][4]).
template <int MI>  // 2 -> BM=128 (x), 4 -> BM=256 (h)
__device__ __forceinline__ void s1_body(
    const float* __restrict__ A, const int KA, const int kbase,
    const _Float16* __restrict__ Bw, _Float16* __restrict__ rbuf,
    const int row0, const int colbase,
    _Float16* __restrict__ AsB, _Float16* __restrict__ BsB) {
  constexpr int ASTR = MI * 64 * 64;   // halves per A buffer

  const int tid = threadIdx.x;
  const int lane = tid & 63;
  const int wv = tid >> 6;
  const int wr = wv >> 1, wc = wv & 1;   // 4x2 wave grid
  const int sr = tid >> 3;               // 0..63
  const int sc = (tid & 7) * 8;

  f32x4 acc[MI][4];
#pragma unroll
  for (int i = 0; i < MI; ++i)
#pragma unroll
    for (int j = 0; j < 4; ++j) acc[i][j] = (f32x4){0.f, 0.f, 0.f, 0.f};

  f32x4 raE[MI][2], raO[MI][2];   // E holds even tiles, O odd (static names)

  auto LOADA = [&](f32x4 (&ra)[MI][2], int it) {   // NON-TEMPORAL stream loads
    const int k0 = kbase + it * 64;
#pragma unroll
    for (int j = 0; j < MI; ++j) {
      const f32x4* s =
          reinterpret_cast<const f32x4*>(A + (size_t)(row0 + j * 64 + sr) * KA + k0 + sc);
      ra[j][0] = __builtin_nontemporal_load(s);
      ra[j][1] = __builtin_nontemporal_load(s + 1);
    }
  };
  auto GLOADB = [&](_Float16* bs, int it) {
    const int k0 = kbase + it * 64;
#pragma unroll
    for (int g = 0; g < 2; ++g) {
      const int rb = wv * 16 + g * 8;              // wave-uniform row base
      const int row = rb + (lane >> 3);            // 8 rows per gload
      const int ch = ((lane & 7) * 8) ^ ((row & 7) << 3);  // inverse swizzle
      gload16(Bw + (size_t)row * KA + k0 + ch, bs + rb * 64);
    }
  };
  auto STOREA = [&](const f32x4 (&ra)[MI][2], _Float16* as) {
#pragma unroll
    for (int j = 0; j < MI; ++j) {
      const int r = j * 64 + sr;
      *reinterpret_cast<half8*>(&as[r * 64 + (sc ^ ((r & 7) << 3))]) =
          cvt8(ra[j][0], ra[j][1]);
    }
  };
  auto COMPUTE = [&](const _Float16* as, const _Float16* bs) {
#pragma unroll
    for (int kk = 0; kk < 64; kk += 32) {
      half8 af[MI], bf[4];
#pragma unroll
      for (int mi = 0; mi < MI; ++mi) {
        const int r = wr * (MI * 16) + mi * 16 + (lane & 15);
        af[mi] = *reinterpret_cast<const half8*>(
            &as[r * 64 + ((kk + 8 * (lane >> 4)) ^ ((r & 7) << 3))]);
      }
#pragma unroll
      for (int ni = 0; ni < 4; ++ni) {
        const int r = wc * 64 + ni * 16 + (lane & 15);
        bf[ni] = *reinterpret_cast<const half8*>(
            &bs[r * 64 + ((kk + 8 * (lane >> 4)) ^ ((r & 7) << 3))]);
      }
#pragma unroll
      for (int mi = 0; mi < MI; ++mi)
#pragma unroll
        for (int ni = 0; ni < 4; ++ni)
          acc[mi][ni] =
              __builtin_amdgcn_mfma_f32_16x16x32_f16(af[mi], bf[ni], acc[mi][ni], 0, 0, 0);
    }
  };
  auto WAIT_COUNTED = [&]() {   // leave the 2*MI newest (A set) in flight
    if constexpr (MI == 2)
      asm volatile("s_waitcnt vmcnt(4)" ::: "memory");
    else
      asm volatile("s_waitcnt vmcnt(8)" ::: "memory");
  };

  _Float16* as0 = AsB;
  _Float16* as1 = AsB + ASTR;
  _Float16* bs0 = BsB;
  _Float16* bs1 = BsB + 128 * 64;

  // prologue: tile0 staged, tile1 A in regs; full drain once.
  GLOADB(bs0, 0);
  LOADA(raE, 0);
  LOADA(raO, 1);
  STOREA(raE, as0);
  asm volatile("s_waitcnt vmcnt(0)" ::: "memory");
  asm volatile("s_waitcnt lgkmcnt(0)" ::: "memory");
  __builtin_amdgcn_s_barrier();
  __builtin_amdgcn_sched_barrier(0);

#pragma unroll 1
  for (int it = 0; it < 16; ++it) {
    const bool more1 = (it + 1 < 16);
    const bool more2 = (it + 2 < 16);
    const bool even = ((it & 1) == 0);
    _Float16* cas = even ? as0 : as1;
    _Float16* cbs = even ? bs0 : bs1;
    _Float16* nas = even ? as1 : as0;
    _Float16* nbs = even ? bs1 : bs0;
    // B for t+1 first (oldest -> retired by counted wait); A for t+2 last.
    if (more1) GLOADB(nbs, it + 1);
    if (more2) {
      if (even) LOADA(raE, it + 2); else LOADA(raO, it + 2);
    }
    __builtin_amdgcn_s_setprio(1);
    COMPUTE(cas, cbs);
    __builtin_amdgcn_s_setprio(0);
    if (more1) {
      if (even) STOREA(raO, nas); else STOREA(raE, nas);  // auto-waits that set
    }
    if (more2) WAIT_COUNTED();                       // B(t+1) landed; A(t+2) flies
    else asm volatile("s_waitcnt vmcnt(0)" ::: "memory");
    asm volatile("s_waitcnt lgkmcnt(0)" ::: "memory");
    __builtin_amdgcn_s_barrier();
    __builtin_amdgcn_sched_barrier(0);
  }

  // D layout (16x16 family): row = 4*(lane>>4)+e, col = lane&15.
#pragma unroll
  for (int mi = 0; mi < MI; ++mi)
#pragma unroll
    for (int ni = 0; ni < 4; ++ni)
#pragma unroll
      for (int e = 0; e < 4; ++e) {
        const int row = row0 + wr * (MI * 16) + mi * 16 + 4 * (lane >> 4) + e;
        const int col = colbase + wc * 64 + ni * 16 + (lane & 15);
        rbuf[(size_t)row * RBLD + col] = (_Float16)acc[mi][ni][e];
      }
}

__global__ __launch_bounds__(512)
void fgrnn_stage1(const float* __restrict__ x, const float* __restrict__ h,
                  const _Float16* __restrict__ wb, _Float16* __restrict__ rbuf) {
  __shared__ _Float16 As[2 * 256 * 64];   // 64 KB (x-blocks use half)
  __shared__ _Float16 Bs[2 * 128 * 64];   // 32 KB
  const int bid = blockIdx.x;
  if (bid < 128) {
    const int mtile = bid >> 1;          // 0..63
    const int ncol = bid & 1;
    s1_body<2>(x, DIN, 0, wb + OFF_W1H + (size_t)(ncol * 128) * DIN, rbuf,
               mtile * 128, ncol * 128, As, Bs);
  } else {
    const int t = bid - 128;
    const int mtile = t >> 2;            // 0..31
    const int kp = (t >> 1) & 1;
    const int ncol = t & 1;
    s1_body<4>(h, DH, kp * 1024, wb + OFF_U1H + (size_t)(ncol * 128) * DH, rbuf,
               mtile * 256, 256 + kp * 256 + ncol * 128, As, Bs);
  }
}

// ---------------- stage 2: pre = [wx | uh0+uh1] @ [W2|U2]^T, K=512 ----------
// 2048 blocks x 256 thr. BM=64, BN=128, 8 iters; 4 waves 2x2, wave 32x64.
// R8-proven structure (~21us), nt state/out in epilogue.
__global__ __launch_bounds__(256)
void fgrnn_stage2(const _Float16* __restrict__ rbuf, const _Float16* __restrict__ wb,
                  const float* __restrict__ state,
                  const float* __restrict__ bg, const float* __restrict__ bu,
                  const float* __restrict__ zeta, const float* __restrict__ nu,
                  float* __restrict__ out) {
  const int bid = blockIdx.x;
  const int L = (bid & 7) * 256 + (bid >> 3);   // XCD swizzle: mtile-banded
  const int mtile = L >> 4;   // 0..127
  const int ntile = L & 15;   // 0..15
  const int row0 = mtile * 64;
  const int col0 = ntile * 128;
  const _Float16* W2h = wb + OFF_W2H;
  const _Float16* U2h = wb + OFF_U2H;

  __shared__ _Float16 As[64 * 64];
  __shared__ _Float16 Bs[128 * 64];

  const int tid = threadIdx.x;
  const int lane = tid & 63;
  const int w = tid >> 6;
  const int wr = w >> 1, wc = w & 1;

  f32x4 acc[2][4];
#pragma unroll
  for (int i = 0; i < 2; ++i)
#pragma unroll
    for (int j = 0; j < 4; ++j) acc[i][j] = (f32x4){0.f, 0.f, 0.f, 0.f};

  const int sr = tid >> 3;      // 0..31
  const int sc = (tid & 7) * 8;

  half8 pa[2], pa2[2], pb[4];

  auto LOADG = [&](int it) {
    const int k0 = it * 64;
    const bool iswx = (k0 < 256);
#pragma unroll
    for (int j = 0; j < 2; ++j) {
      const _Float16* p = rbuf + (size_t)(row0 + j * 32 + sr) * RBLD + k0 + sc;
      pa[j] = *reinterpret_cast<const half8*>(p);
      if (!iswx) pa2[j] = *reinterpret_cast<const half8*>(p + 256);  // uh1 panel
    }
    const _Float16* Bh = iswx ? W2h : U2h;
    const int kb = k0 & 255;
#pragma unroll
    for (int j = 0; j < 4; ++j)
      pb[j] = *reinterpret_cast<const half8*>(Bh + (size_t)(col0 + j * 32 + sr) * RK + kb + sc);
  };
  auto STORE = [&](int it) {
    const int k0 = it * 64;
#pragma unroll
    for (int j = 0; j < 2; ++j) {
      half8 v = pa[j];
      if (k0 >= 256) v = v + pa2[j];   // uh = uh0 + uh1 (v_pk_add_f16)
      const int r = j * 32 + sr;
      *reinterpret_cast<half8*>(&As[r * 64 + (sc ^ ((r & 7) << 3))]) = v;
    }
#pragma unroll
    for (int j = 0; j < 4; ++j) {
      const int r = j * 32 + sr;
      *reinterpret_cast<half8*>(&Bs[r * 64 + (sc ^ ((r & 7) << 3))]) = pb[j];
    }
  };

  LOADG(0);
  STORE(0);
  __syncthreads();

  for (int it = 0; it < 8; ++it) {
    const bool more = (it + 1 < 8);
    if (more) LOADG(it + 1);
#pragma unroll
    for (int kk = 0; kk < 64; kk += 32) {
      half8 af[2], bf[4];
#pragma unroll
      for (int mi = 0; mi < 2; ++mi) {
        const int r = wr * 32 + mi * 16 + (lane & 15);
        af[mi] = *reinterpret_cast<const half8*>(
            &As[r * 64 + ((kk + 8 * (lane >> 4)) ^ ((r & 7) << 3))]);
      }
#pragma unroll
      for (int ni = 0; ni < 4; ++ni) {
        const int r = wc * 64 + ni * 16 + (lane & 15);
        bf[ni] = *reinterpret_cast<const half8*>(
            &Bs[r * 64 + ((kk + 8 * (lane >> 4)) ^ ((r & 7) << 3))]);
      }
#pragma unroll
      for (int mi = 0; mi < 2; ++mi)
#pragma unroll
        for (int ni = 0; ni < 4; ++ni)
          acc[mi][ni] =
              __builtin_amdgcn_mfma_f32_16x16x32_f16(af[mi], bf[ni], acc[mi][ni], 0, 0, 0);
    }
    if (more) {
      __syncthreads();
      STORE(it + 1);
    }
    __syncthreads();
  }

  // Fused epilogue (fast exp2/rcp; asymptotes correct). state/out streamed nt.
  const float LOG2E = 1.44269504f;
  const float sz = __builtin_amdgcn_rcpf(1.f + __builtin_amdgcn_exp2f(-zeta[0] * LOG2E));
  const float sn = __builtin_amdgcn_rcpf(1.f + __builtin_amdgcn_exp2f(-nu[0] * LOG2E));
#pragma unroll
  for (int mi = 0; mi < 2; ++mi)
#pragma unroll
    for (int ni = 0; ni < 4; ++ni) {
      const int col = col0 + wc * 64 + ni * 16 + (lane & 15);
      const float bgc = bg[col];
      const float buc = bu[col];
#pragma unroll
      for (int e = 0; e < 4; ++e) {
        const int row = row0 + wr * 32 + mi * 16 + 4 * (lane >> 4) + e;
        const float pre = acc[mi][ni][e];
        const float zg =
            __builtin_amdgcn_rcpf(1.f + __builtin_amdgcn_exp2f(-(pre + bgc) * LOG2E));
        const float hc =
            1.f - 2.f * __builtin_amdgcn_rcpf(
                            1.f + __builtin_amdgcn_exp2f((pre + buc) * (2.f * LOG2E)));
        const float sv = __builtin_nontemporal_load(&state[(size_t)row * DH + col]);
        __builtin_nontemporal_store(zg * sv + (sz * (1.f - zg) + sn) * hc,
                                    &out[(size_t)row * DH + col]);
      }
    }
}

extern "C" void kernel_launch(void* const* d_in, const int* in_sizes, int n_in,
                              void* d_out, int out_size, void* d_ws, size_t ws_size,
                              hipStream_t stream) {
  const float* input = (const float*)d_in[0];
  const float* state = (const float*)d_in[1];
  const float* W1 = (const float*)d_in[2];
  const float* W2 = (const float*)d_in[3];
  const float* U1 = (const float*)d_in[4];
  const float* U2 = (const float*)d_in[5];
  const float* bg = (const float*)d_in[6];
  const float* bu = (const float*)d_in[7];
  const float* zeta = (const float*)d_in[8];
  const float* nu = (const float*)d_in[9];
  float* out = (float*)d_out;

  _Float16* rbuf = (_Float16*)d_ws;                     // 8192*768*2 = 12.6 MB
  _Float16* wb = rbuf + (size_t)8192 * RBLD;            // +3.67 MB f16 weights

  fgrnn_prep<<<1792, 256, 0, stream>>>(W1, U1, W2, U2, wb);
  fgrnn_stage1<<<256, 512, 0, stream>>>(input, state, wb, rbuf);
  fgrnn_stage2<<<2048, 256, 0, stream>>>(rbuf, wb, state, bg, bu, zeta, nu, out);
}

// Round 14
// 105.159 us; speedup vs baseline: 1.2080x; 1.2080x over previous
//
#include <hip/hip_runtime.h>
#include <hip/hip_fp16.h>
#include <cstdint>
#include <cstddef>

// FastGRNN cell, MI355X fp16-MFMA, v14 = R10 + L3-warm prefetch prologue.
// prep:   weights f32->f16 into wb.
// stage1: 1536 blocks x 256 thr (6/CU), BM=64 BN=128 K=512 (8 it), 24KB LDS.
//         PROLOGUE: 4 fire-and-forget dword loads/thread warm the block's
//         128KB A-region into L2/L3 (sunk at kernel end) -> main-loop A loads
//         hit cache latency instead of HBM latency (MSHR-limited delivery
//         scales ~1/latency). 6 K-split panels -> rb6[8192][1536] f16.
// reduce: rb6 -> rb2[8192][512] (wx = p0+p1, uh = p2+..+p5), deterministic.
// stage2: pre = rb2 @ [W2|U2]^T (K=512) + fused sigmoid/tanh epilogue.

typedef _Float16 half8 __attribute__((ext_vector_type(8)));
typedef float f32x4 __attribute__((ext_vector_type(4)));

#define DIN 1024
#define DH 2048
#define RK 256
#define RB6LD 1536
// wb half-offsets
#define OFF_W1H 0
#define OFF_U1H 262144
#define OFF_W2H 786432
#define OFF_U2H 1310720

__device__ __forceinline__ half8 cvt8(const float4 a, const float4 b) {
  half8 h;
  h[0] = (_Float16)a.x; h[1] = (_Float16)a.y; h[2] = (_Float16)a.z; h[3] = (_Float16)a.w;
  h[4] = (_Float16)b.x; h[5] = (_Float16)b.y; h[6] = (_Float16)b.z; h[7] = (_Float16)b.w;
  return h;
}

// ---------------- prep: weights f32 -> f16 ----------------------------------
__global__ __launch_bounds__(256)
void fgrnn_prep(const float* __restrict__ W1, const float* __restrict__ U1,
                const float* __restrict__ W2, const float* __restrict__ U2,
                _Float16* __restrict__ wb) {
  const int q = blockIdx.x * 256 + threadIdx.x;
  const float* src;
  int rel;
  if (q < 65536) { src = W1; rel = q; }
  else if (q < 196608) { src = U1; rel = q - 65536; }
  else if (q < 327680) { src = W2; rel = q - 196608; }
  else { src = U2; rel = q - 327680; }
  const float4 v = reinterpret_cast<const float4*>(src)[rel];
  union { _Float16 h[4]; uint2 u; } cv;
  cv.h[0] = (_Float16)v.x; cv.h[1] = (_Float16)v.y;
  cv.h[2] = (_Float16)v.z; cv.h[3] = (_Float16)v.w;
  reinterpret_cast<uint2*>(wb)[q] = cv.u;
}

// ---------------- stage 1: R10 structure + A-region L3 warm -----------------
// 1536 blocks x 256 thr. BM=64, BN=128, BK=64, 8 iters. 4 waves 2x2,
// wave tile 32x64 (acc[2][4]). panel p: p<2 -> x@W1^T kslice p;
// p>=2 -> h@U1^T kslice p-2. ncol picks weight rows ncol*128..+128.
__global__ __launch_bounds__(256)
void fgrnn_stage1(const float* __restrict__ x, const float* __restrict__ h,
                  const _Float16* __restrict__ wb, _Float16* __restrict__ rb6) {
  const int bid = blockIdx.x;
  const int L = (bid & 7) * 192 + (bid >> 3);  // XCD chunk swizzle (1536=8*192)
  const int p = L >> 8;                        // 0..5 panel
  const int rem = L & 255;
  const int ncol = rem >> 7;                   // 0,1
  const int mtile = rem & 127;                 // 0..127
  const bool isx = (p < 2);
  const float* A = isx ? x : h;
  const int KA = isx ? DIN : DH;
  const int kbase = (isx ? p : (p - 2)) * 512;
  const _Float16* Bw = wb + (isx ? OFF_W1H : OFF_U1H) + (size_t)(ncol * 128) * KA;
  const int row0 = mtile * 64;
  const int colbase = p * 256 + ncol * 128;

  __shared__ _Float16 As[64 * 64];    // 8 KB  (XOR swizzle: c ^= (r&7)<<3)
  __shared__ _Float16 Bs[128 * 64];   // 16 KB

  const int tid = threadIdx.x;
  const int lane = tid & 63;
  const int w = tid >> 6;
  const int wr = w >> 1, wc = w & 1;

  // ---- L3-warm prologue: 1 dword per 128B line of this block's A region ----
  // A region = 64 rows x 512 f32 = 128 KB = 1024 lines; 4 lines/thread.
  float sink0, sink1, sink2, sink3;
  {
    const float* pb = A + (size_t)row0 * KA + kbase;
    const int l0 = tid;          // line index 0..255
    const int l1 = tid + 256;
    const int l2 = tid + 512;
    const int l3 = tid + 768;
    sink0 = pb[(size_t)(l0 >> 4) * KA + (l0 & 15) * 32];
    sink1 = pb[(size_t)(l1 >> 4) * KA + (l1 & 15) * 32];
    sink2 = pb[(size_t)(l2 >> 4) * KA + (l2 & 15) * 32];
    sink3 = pb[(size_t)(l3 >> 4) * KA + (l3 & 15) * 32];
  }

  f32x4 acc[2][4];
#pragma unroll
  for (int i = 0; i < 2; ++i)
#pragma unroll
    for (int j = 0; j < 4; ++j) acc[i][j] = (f32x4){0.f, 0.f, 0.f, 0.f};

  const int sr = tid >> 3;      // 0..31
  const int sc = (tid & 7) * 8;

  float4 pa4[2][2];
  half8 pb[4];

  auto LOADG = [&](int it) {
    const int k0 = kbase + it * 64;
#pragma unroll
    for (int j = 0; j < 2; ++j) {
      const float* s = A + (size_t)(row0 + j * 32 + sr) * KA + k0 + sc;
      pa4[j][0] = *reinterpret_cast<const float4*>(s);
      pa4[j][1] = *reinterpret_cast<const float4*>(s + 4);
    }
#pragma unroll
    for (int j = 0; j < 4; ++j)
      pb[j] = *reinterpret_cast<const half8*>(Bw + (size_t)(j * 32 + sr) * KA + k0 + sc);
  };
  auto STORE = [&]() {
#pragma unroll
    for (int j = 0; j < 2; ++j) {
      const int r = j * 32 + sr;
      *reinterpret_cast<half8*>(&As[r * 64 + (sc ^ ((r & 7) << 3))]) =
          cvt8(pa4[j][0], pa4[j][1]);
    }
#pragma unroll
    for (int j = 0; j < 4; ++j) {
      const int r = j * 32 + sr;
      *reinterpret_cast<half8*>(&Bs[r * 64 + (sc ^ ((r & 7) << 3))]) = pb[j];
    }
  };

  LOADG(0);
  STORE();
  __syncthreads();

  for (int it = 0; it < 8; ++it) {
    const bool more = (it + 1 < 8);
    if (more) LOADG(it + 1);
#pragma unroll
    for (int kk = 0; kk < 64; kk += 32) {
      half8 af[2], bf[4];
#pragma unroll
      for (int mi = 0; mi < 2; ++mi) {
        const int r = wr * 32 + mi * 16 + (lane & 15);
        af[mi] = *reinterpret_cast<const half8*>(
            &As[r * 64 + ((kk + 8 * (lane >> 4)) ^ ((r & 7) << 3))]);
      }
#pragma unroll
      for (int ni = 0; ni < 4; ++ni) {
        const int r = wc * 64 + ni * 16 + (lane & 15);
        bf[ni] = *reinterpret_cast<const half8*>(
            &Bs[r * 64 + ((kk + 8 * (lane >> 4)) ^ ((r & 7) << 3))]);
      }
#pragma unroll
      for (int mi = 0; mi < 2; ++mi)
#pragma unroll
        for (int ni = 0; ni < 4; ++ni)
          acc[mi][ni] =
              __builtin_amdgcn_mfma_f32_16x16x32_f16(af[mi], bf[ni], acc[mi][ni], 0, 0, 0);
    }
    if (more) {
      __syncthreads();
      STORE();
    }
    __syncthreads();
  }

  // D layout (16x16 family): row = 4*(lane>>4)+e, col = lane&15.
#pragma unroll
  for (int mi = 0; mi < 2; ++mi)
#pragma unroll
    for (int ni = 0; ni < 4; ++ni)
#pragma unroll
      for (int e = 0; e < 4; ++e) {
        const int row = row0 + wr * 32 + mi * 16 + 4 * (lane >> 4) + e;
        const int col = colbase + wc * 64 + ni * 16 + (lane & 15);
        rb6[(size_t)row * RB6LD + col] = (_Float16)acc[mi][ni][e];
      }

  // keep the warm loads alive (rule #17: anti-DCE sink, placed at end so no
  // mid-loop waitcnt is forced on them)
  asm volatile("" :: "v"(sink0), "v"(sink1), "v"(sink2), "v"(sink3));
}

// ---------------- reduce: rb6[8192][1536] -> rb2[8192][512] -----------------
// Deterministic fixed-order panel sums. 2048 blocks x 256 thr; one half8 each.
__global__ __launch_bounds__(256)
void fgrnn_reduce(const _Float16* __restrict__ rb6, _Float16* __restrict__ rb2) {
  const int t = blockIdx.x * 256 + threadIdx.x;  // 0..524287
  const int row = t >> 6;
  const int ch = t & 63;
  const _Float16* src = rb6 + (size_t)row * RB6LD;
  half8 s;
  int outcol;
  if (ch < 32) {  // wx = p0 + p1
    const int c = ch * 8;
    s = *reinterpret_cast<const half8*>(src + c) +
        *reinterpret_cast<const half8*>(src + 256 + c);
    outcol = c;
  } else {        // uh = p2 + p3 + p4 + p5
    const int c = (ch - 32) * 8;
    const _Float16* su = src + 512;
    s = *reinterpret_cast<const half8*>(su + c) +
        *reinterpret_cast<const half8*>(su + 256 + c);
    s = s + *reinterpret_cast<const half8*>(su + 512 + c);
    s = s + *reinterpret_cast<const half8*>(su + 768 + c);
    outcol = 256 + c;
  }
  *reinterpret_cast<half8*>(rb2 + (size_t)row * 512 + outcol) = s;
}

// ---------------- stage 2: pre = rb2 @ [W2|U2]^T, K=512 ---------------------
// 2048 blocks x 256 threads. BM=64, BN=128, BK=64, 8 iters; 4 waves 2x2.
__global__ __launch_bounds__(256)
void fgrnn_stage2(const _Float16* __restrict__ rb2, const _Float16* __restrict__ wb,
                  const float* __restrict__ state,
                  const float* __restrict__ bg, const float* __restrict__ bu,
                  const float* __restrict__ zeta, const float* __restrict__ nu,
                  float* __restrict__ out) {
  const int bid = blockIdx.x;
  const int L = (bid & 7) * 256 + (bid >> 3);   // XCD swizzle: mtile-banded
  const int mtile = L >> 4;   // 0..127
  const int ntile = L & 15;   // 0..15
  const int row0 = mtile * 64;
  const int col0 = ntile * 128;
  const _Float16* W2h = wb + OFF_W2H;
  const _Float16* U2h = wb + OFF_U2H;

  __shared__ _Float16 As[64 * 64];
  __shared__ _Float16 Bs[128 * 64];

  const int tid = threadIdx.x;
  const int lane = tid & 63;
  const int w = tid >> 6;
  const int wr = w >> 1, wc = w & 1;

  f32x4 acc[2][4];
#pragma unroll
  for (int i = 0; i < 2; ++i)
#pragma unroll
    for (int j = 0; j < 4; ++j) acc[i][j] = (f32x4){0.f, 0.f, 0.f, 0.f};

  const int sr = tid >> 3;      // 0..31
  const int sc = (tid & 7) * 8;

  half8 pa[2], pb[4];

  auto LOADG = [&](int it) {
    const int k0 = it * 64;
#pragma unroll
    for (int j = 0; j < 2; ++j)
      pa[j] = *reinterpret_cast<const half8*>(rb2 + (size_t)(row0 + j * 32 + sr) * 512 + k0 + sc);
    const _Float16* Bh = (k0 < 256) ? W2h : U2h;
    const int kb = k0 & 255;
#pragma unroll
    for (int j = 0; j < 4; ++j)
      pb[j] = *reinterpret_cast<const half8*>(Bh + (size_t)(col0 + j * 32 + sr) * RK + kb + sc);
  };
  auto STORE = [&]() {
#pragma unroll
    for (int j = 0; j < 2; ++j) {
      const int r = j * 32 + sr;
      *reinterpret_cast<half8*>(&As[r * 64 + (sc ^ ((r & 7) << 3))]) = pa[j];
    }
#pragma unroll
    for (int j = 0; j < 4; ++j) {
      const int r = j * 32 + sr;
      *reinterpret_cast<half8*>(&Bs[r * 64 + (sc ^ ((r & 7) << 3))]) = pb[j];
    }
  };

  LOADG(0);
  STORE();
  __syncthreads();

  for (int it = 0; it < 8; ++it) {
    const bool more = (it + 1 < 8);
    if (more) LOADG(it + 1);
#pragma unroll
    for (int kk = 0; kk < 64; kk += 32) {
      half8 af[2], bf[4];
#pragma unroll
      for (int mi = 0; mi < 2; ++mi) {
        const int r = wr * 32 + mi * 16 + (lane & 15);
        af[mi] = *reinterpret_cast<const half8*>(
            &As[r * 64 + ((kk + 8 * (lane >> 4)) ^ ((r & 7) << 3))]);
      }
#pragma unroll
      for (int ni = 0; ni < 4; ++ni) {
        const int r = wc * 64 + ni * 16 + (lane & 15);
        bf[ni] = *reinterpret_cast<const half8*>(
            &Bs[r * 64 + ((kk + 8 * (lane >> 4)) ^ ((r & 7) << 3))]);
      }
#pragma unroll
      for (int mi = 0; mi < 2; ++mi)
#pragma unroll
        for (int ni = 0; ni < 4; ++ni)
          acc[mi][ni] =
              __builtin_amdgcn_mfma_f32_16x16x32_f16(af[mi], bf[ni], acc[mi][ni], 0, 0, 0);
    }
    if (more) {
      __syncthreads();
      STORE();
    }
    __syncthreads();
  }

  // Fused epilogue (fast exp2/rcp; asymptotes correct)
  const float LOG2E = 1.44269504f;
  const float sz = __builtin_amdgcn_rcpf(1.f + __builtin_amdgcn_exp2f(-zeta[0] * LOG2E));
  const float sn = __builtin_amdgcn_rcpf(1.f + __builtin_amdgcn_exp2f(-nu[0] * LOG2E));
#pragma unroll
  for (int mi = 0; mi < 2; ++mi)
#pragma unroll
    for (int ni = 0; ni < 4; ++ni) {
      const int col = col0 + wc * 64 + ni * 16 + (lane & 15);
      const float bgc = bg[col];
      const float buc = bu[col];
#pragma unroll
      for (int e = 0; e < 4; ++e) {
        const int row = row0 + wr * 32 + mi * 16 + 4 * (lane >> 4) + e;
        const float pre = acc[mi][ni][e];
        const float zg =
            __builtin_amdgcn_rcpf(1.f + __builtin_amdgcn_exp2f(-(pre + bgc) * LOG2E));
        const float hc =
            1.f - 2.f * __builtin_amdgcn_rcpf(
                            1.f + __builtin_amdgcn_exp2f((pre + buc) * (2.f * LOG2E)));
        const float sv = state[(size_t)row * DH + col];
        out[(size_t)row * DH + col] = zg * sv + (sz * (1.f - zg) + sn) * hc;
      }
    }
}

extern "C" void kernel_launch(void* const* d_in, const int* in_sizes, int n_in,
                              void* d_out, int out_size, void* d_ws, size_t ws_size,
                              hipStream_t stream) {
  const float* input = (const float*)d_in[0];
  const float* state = (const float*)d_in[1];
  const float* W1 = (const float*)d_in[2];
  const float* W2 = (const float*)d_in[3];
  const float* U1 = (const float*)d_in[4];
  const float* U2 = (const float*)d_in[5];
  const float* bg = (const float*)d_in[6];
  const float* bu = (const float*)d_in[7];
  const float* zeta = (const float*)d_in[8];
  const float* nu = (const float*)d_in[9];
  float* out = (float*)d_out;

  _Float16* rb6 = (_Float16*)d_ws;                      // 8192*1536*2 = 25.2 MB
  _Float16* rb2 = rb6 + (size_t)8192 * RB6LD;           // 8.4 MB
  _Float16* wb = rb2 + (size_t)8192 * 512;              // 3.67 MB (37.3 MB total)

  fgrnn_prep<<<1792, 256, 0, stream>>>(W1, U1, W2, U2, wb);
  fgrnn_stage1<<<1536, 256, 0, stream>>>(input, state, wb, rb6);
  fgrnn_reduce<<<2048, 256, 0, stream>>>(rb6, rb2);
  fgrnn_stage2<<<2048, 256, 0, stream>>>(rb2, wb, state, bg, bu, zeta, nu, out);
}

// Round 15
// 85.958 us; speedup vs baseline: 1.4779x; 1.2234x over previous
//
#include <hip/hip_runtime.h>
#include <hip/hip_fp16.h>
#include <cstdint>
#include <cstddef>

// FastGRNN cell, MI355X fp16-MFMA, v15.
// stage1: FULLY-ASYNC staging — A (f32) and B (f16) both via global_load_lds
//         (no register round-trip -> no per-wave in-order-retirement stall on
//         HBM misses). BK=32, 16 iters, 3 LDS buffers, counted vmcnt(4) gives
//         each tile ~2 iters of flight time. 1536 blocks x 256 thr, 48KB LDS.
// reduce: rb6[8192][1536] -> rb2[8192][512] deterministic panel sums.
// stage2: pre = rb2 @ [W2|U2]^T (K=512) + fused sigmoid/tanh epilogue (proven).

typedef _Float16 half8 __attribute__((ext_vector_type(8)));
typedef float f32x4 __attribute__((ext_vector_type(4)));

#define DIN 1024
#define DH 2048
#define RK 256
#define RB6LD 1536
// wb half-offsets
#define OFF_W1H 0
#define OFF_U1H 262144
#define OFF_W2H 786432
#define OFF_U2H 1310720

__device__ __forceinline__ half8 cvt8f(f32x4 a, f32x4 b) {
  half8 h;
  h[0] = (_Float16)a[0]; h[1] = (_Float16)a[1]; h[2] = (_Float16)a[2]; h[3] = (_Float16)a[3];
  h[4] = (_Float16)b[0]; h[5] = (_Float16)b[1]; h[6] = (_Float16)b[2]; h[7] = (_Float16)b[3];
  return h;
}
__device__ __forceinline__ half8 cvt8(const float4 a, const float4 b) {
  half8 h;
  h[0] = (_Float16)a.x; h[1] = (_Float16)a.y; h[2] = (_Float16)a.z; h[3] = (_Float16)a.w;
  h[4] = (_Float16)b.x; h[5] = (_Float16)b.y; h[6] = (_Float16)b.z; h[7] = (_Float16)b.w;
  return h;
}

// 16B global->LDS direct copy; LDS dest = wave-uniform base + lane*16.
__device__ __forceinline__ void gload16(const void* g, void* lds) {
  __builtin_amdgcn_global_load_lds(
      (const __attribute__((address_space(1))) unsigned*)g,
      (__attribute__((address_space(3))) unsigned*)lds, 16, 0, 0);
}

// ---------------- prep: weights f32 -> f16 ----------------------------------
__global__ __launch_bounds__(256)
void fgrnn_prep(const float* __restrict__ W1, const float* __restrict__ U1,
                const float* __restrict__ W2, const float* __restrict__ U2,
                _Float16* __restrict__ wb) {
  const int q = blockIdx.x * 256 + threadIdx.x;
  const float* src;
  int rel;
  if (q < 65536) { src = W1; rel = q; }
  else if (q < 196608) { src = U1; rel = q - 65536; }
  else if (q < 327680) { src = W2; rel = q - 196608; }
  else { src = U2; rel = q - 327680; }
  const float4 v = reinterpret_cast<const float4*>(src)[rel];
  union { _Float16 h[4]; uint2 u; } cv;
  cv.h[0] = (_Float16)v.x; cv.h[1] = (_Float16)v.y;
  cv.h[2] = (_Float16)v.z; cv.h[3] = (_Float16)v.w;
  reinterpret_cast<uint2*>(wb)[q] = cv.u;
}

// ---------------- stage 1: all-async staging, 3-buffer pipeline -------------
// 1536 blocks x 256 thr. BM=64, BN=128, BK=32, 16 iters. 4 waves 2x2, wave
// tile 32x64 (acc[2][4]). panel p<2: x@W1^T kslice p; p>=2: h@U1^T kslice p-2.
// A LDS [64][32] f32, 16B-chunk swizzle ch^=(r&7); B LDS [128][32] f16,
// chunk swizzle ch^=((r>>2)&3). Both applied on the GLOBAL source address
// (rule #21: linear dest + inverse-swizzled source + swizzled read).
__global__ __launch_bounds__(256)
void fgrnn_stage1(const float* __restrict__ x, const float* __restrict__ h,
                  const _Float16* __restrict__ wb, _Float16* __restrict__ rb6) {
  __shared__ float Af[3][64 * 32];       // 3 x 8 KB
  __shared__ _Float16 Bf[3][128 * 32];   // 3 x 8 KB

  const int bid = blockIdx.x;
  const int L = (bid & 7) * 192 + (bid >> 3);  // XCD chunk swizzle (1536=8*192)
  const int p = L >> 8;                        // 0..5 panel
  const int rem = L & 255;
  const int ncol = rem >> 7;                   // 0,1
  const int mtile = rem & 127;                 // 0..127
  const bool isx = (p < 2);
  const float* A = isx ? x : h;
  const int KA = isx ? DIN : DH;
  const int kbase = (isx ? p : (p - 2)) * 512;
  const _Float16* Bw = wb + (isx ? OFF_W1H : OFF_U1H) + (size_t)(ncol * 128) * KA;
  const int row0 = mtile * 64;
  const int colbase = p * 256 + ncol * 128;

  const int tid = threadIdx.x;
  const int lane = tid & 63;
  const int wv = tid >> 6;
  const int wr = wv >> 1, wc = wv & 1;

  f32x4 acc[2][4];
#pragma unroll
  for (int i = 0; i < 2; ++i)
#pragma unroll
    for (int j = 0; j < 4; ++j) acc[i][j] = (f32x4){0.f, 0.f, 0.f, 0.f};

  // per-lane source-permuted addresses (constant across iters except k0)
  const int aRowL = (lane >> 3);              // 0..7 within 8-row gload
  const int aCh = (lane & 7) ^ aRowL;         // A source 16B-chunk (4 f32)
  const int bRowL = (lane >> 2);              // 0..15 within 16-row gload
  const int bCh = (lane & 3) ^ (lane >> 4);   // B source 16B-chunk (8 f16)

  auto GLOAD = [&](int buf, int it) {
    const int k0 = kbase + it * 32;
    // A: 2 gloads x 8 rows (1KB each), dest linear
#pragma unroll
    for (int g = 0; g < 2; ++g) {
      const int rb = wv * 16 + g * 8;
      gload16(A + (size_t)(row0 + rb + aRowL) * KA + k0 + aCh * 4,
              &Af[buf][rb * 32]);
    }
    // B: 2 gloads x 16 rows (1KB each)
#pragma unroll
    for (int g = 0; g < 2; ++g) {
      const int rb = wv * 32 + g * 16;
      gload16(Bw + (size_t)(rb + bRowL) * KA + k0 + bCh * 8,
              &Bf[buf][rb * 32]);
    }
  };

  auto COMPUTE = [&](int buf) {
    half8 af[2], bf[4];
    const int g = lane >> 4;
#pragma unroll
    for (int mi = 0; mi < 2; ++mi) {
      const int r = wr * 32 + mi * 16 + (lane & 15);
      const int c0 = (2 * g) ^ (r & 7);
      const int c1 = (2 * g + 1) ^ (r & 7);
      const f32x4 lo = *reinterpret_cast<const f32x4*>(&Af[buf][r * 32 + c0 * 4]);
      const f32x4 hi = *reinterpret_cast<const f32x4*>(&Af[buf][r * 32 + c1 * 4]);
      af[mi] = cvt8f(lo, hi);
    }
#pragma unroll
    for (int ni = 0; ni < 4; ++ni) {
      const int r = wc * 64 + ni * 16 + (lane & 15);
      const int c = g ^ ((r >> 2) & 3);
      bf[ni] = *reinterpret_cast<const half8*>(&Bf[buf][r * 32 + c * 8]);
    }
#pragma unroll
    for (int mi = 0; mi < 2; ++mi)
#pragma unroll
      for (int ni = 0; ni < 4; ++ni)
        acc[mi][ni] =
            __builtin_amdgcn_mfma_f32_16x16x32_f16(af[mi], bf[ni], acc[mi][ni], 0, 0, 0);
  };

  // prologue: tiles 0,1 in flight; wait tile 0 (in-order retirement).
  GLOAD(0, 0);
  GLOAD(1, 1);
  asm volatile("s_waitcnt vmcnt(4)" ::: "memory");
  __builtin_amdgcn_s_barrier();
  __builtin_amdgcn_sched_barrier(0);

#pragma unroll
  for (int t = 0; t < 16; ++t) {
    if (t + 2 < 16) GLOAD((t + 2) % 3, t + 2);
    __builtin_amdgcn_s_setprio(1);
    COMPUTE(t % 3);
    __builtin_amdgcn_s_setprio(0);
    // buf[t+1] must be resident before next iter; leave buf[t+2]'s 4 in flight.
    if (t + 2 < 16) {
      asm volatile("s_waitcnt vmcnt(4)" ::: "memory");
    } else if (t + 1 < 16) {
      asm volatile("s_waitcnt vmcnt(0)" ::: "memory");
    }
    __builtin_amdgcn_s_barrier();
    __builtin_amdgcn_sched_barrier(0);
  }

  // D layout (16x16 family): row = 4*(lane>>4)+e, col = lane&15.
#pragma unroll
  for (int mi = 0; mi < 2; ++mi)
#pragma unroll
    for (int ni = 0; ni < 4; ++ni)
#pragma unroll
      for (int e = 0; e < 4; ++e) {
        const int row = row0 + wr * 32 + mi * 16 + 4 * (lane >> 4) + e;
        const int col = colbase + wc * 64 + ni * 16 + (lane & 15);
        rb6[(size_t)row * RB6LD + col] = (_Float16)acc[mi][ni][e];
      }
}

// ---------------- reduce: rb6[8192][1536] -> rb2[8192][512] -----------------
__global__ __launch_bounds__(256)
void fgrnn_reduce(const _Float16* __restrict__ rb6, _Float16* __restrict__ rb2) {
  const int t = blockIdx.x * 256 + threadIdx.x;  // 0..524287
  const int row = t >> 6;
  const int ch = t & 63;
  const _Float16* src = rb6 + (size_t)row * RB6LD;
  half8 s;
  int outcol;
  if (ch < 32) {  // wx = p0 + p1
    const int c = ch * 8;
    s = *reinterpret_cast<const half8*>(src + c) +
        *reinterpret_cast<const half8*>(src + 256 + c);
    outcol = c;
  } else {        // uh = p2 + p3 + p4 + p5
    const int c = (ch - 32) * 8;
    const _Float16* su = src + 512;
    s = *reinterpret_cast<const half8*>(su + c) +
        *reinterpret_cast<const half8*>(su + 256 + c);
    s = s + *reinterpret_cast<const half8*>(su + 512 + c);
    s = s + *reinterpret_cast<const half8*>(su + 768 + c);
    outcol = 256 + c;
  }
  *reinterpret_cast<half8*>(rb2 + (size_t)row * 512 + outcol) = s;
}

// ---------------- stage 2: pre = rb2 @ [W2|U2]^T, K=512 (proven) ------------
__global__ __launch_bounds__(256)
void fgrnn_stage2(const _Float16* __restrict__ rb2, const _Float16* __restrict__ wb,
                  const float* __restrict__ state,
                  const float* __restrict__ bg, const float* __restrict__ bu,
                  const float* __restrict__ zeta, const float* __restrict__ nu,
                  float* __restrict__ out) {
  const int bid = blockIdx.x;
  const int L = (bid & 7) * 256 + (bid >> 3);   // XCD swizzle: mtile-banded
  const int mtile = L >> 4;   // 0..127
  const int ntile = L & 15;   // 0..15
  const int row0 = mtile * 64;
  const int col0 = ntile * 128;
  const _Float16* W2h = wb + OFF_W2H;
  const _Float16* U2h = wb + OFF_U2H;

  __shared__ _Float16 As[64 * 64];
  __shared__ _Float16 Bs[128 * 64];

  const int tid = threadIdx.x;
  const int lane = tid & 63;
  const int w = tid >> 6;
  const int wr = w >> 1, wc = w & 1;

  f32x4 acc[2][4];
#pragma unroll
  for (int i = 0; i < 2; ++i)
#pragma unroll
    for (int j = 0; j < 4; ++j) acc[i][j] = (f32x4){0.f, 0.f, 0.f, 0.f};

  const int sr = tid >> 3;      // 0..31
  const int sc = (tid & 7) * 8;

  half8 pa[2], pb[4];

  auto LOADG = [&](int it) {
    const int k0 = it * 64;
#pragma unroll
    for (int j = 0; j < 2; ++j)
      pa[j] = *reinterpret_cast<const half8*>(rb2 + (size_t)(row0 + j * 32 + sr) * 512 + k0 + sc);
    const _Float16* Bh = (k0 < 256) ? W2h : U2h;
    const int kb = k0 & 255;
#pragma unroll
    for (int j = 0; j < 4; ++j)
      pb[j] = *reinterpret_cast<const half8*>(Bh + (size_t)(col0 + j * 32 + sr) * RK + kb + sc);
  };
  auto STORE = [&]() {
#pragma unroll
    for (int j = 0; j < 2; ++j) {
      const int r = j * 32 + sr;
      *reinterpret_cast<half8*>(&As[r * 64 + (sc ^ ((r & 7) << 3))]) = pa[j];
    }
#pragma unroll
    for (int j = 0; j < 4; ++j) {
      const int r = j * 32 + sr;
      *reinterpret_cast<half8*>(&Bs[r * 64 + (sc ^ ((r & 7) << 3))]) = pb[j];
    }
  };

  LOADG(0);
  STORE();
  __syncthreads();

  for (int it = 0; it < 8; ++it) {
    const bool more = (it + 1 < 8);
    if (more) LOADG(it + 1);
#pragma unroll
    for (int kk = 0; kk < 64; kk += 32) {
      half8 af[2], bf[4];
#pragma unroll
      for (int mi = 0; mi < 2; ++mi) {
        const int r = wr * 32 + mi * 16 + (lane & 15);
        af[mi] = *reinterpret_cast<const half8*>(
            &As[r * 64 + ((kk + 8 * (lane >> 4)) ^ ((r & 7) << 3))]);
      }
#pragma unroll
      for (int ni = 0; ni < 4; ++ni) {
        const int r = wc * 64 + ni * 16 + (lane & 15);
        bf[ni] = *reinterpret_cast<const half8*>(
            &Bs[r * 64 + ((kk + 8 * (lane >> 4)) ^ ((r & 7) << 3))]);
      }
#pragma unroll
      for (int mi = 0; mi < 2; ++mi)
#pragma unroll
        for (int ni = 0; ni < 4; ++ni)
          acc[mi][ni] =
              __builtin_amdgcn_mfma_f32_16x16x32_f16(af[mi], bf[ni], acc[mi][ni], 0, 0, 0);
    }
    if (more) {
      __syncthreads();
      STORE();
    }
    __syncthreads();
  }

  // Fused epilogue (fast exp2/rcp; asymptotes correct)
  const float LOG2E = 1.44269504f;
  const float sz = __builtin_amdgcn_rcpf(1.f + __builtin_amdgcn_exp2f(-zeta[0] * LOG2E));
  const float sn = __builtin_amdgcn_rcpf(1.f + __builtin_amdgcn_exp2f(-nu[0] * LOG2E));
#pragma unroll
  for (int mi = 0; mi < 2; ++mi)
#pragma unroll
    for (int ni = 0; ni < 4; ++ni) {
      const int col = col0 + wc * 64 + ni * 16 + (lane & 15);
      const float bgc = bg[col];
      const float buc = bu[col];
#pragma unroll
      for (int e = 0; e < 4; ++e) {
        const int row = row0 + wr * 32 + mi * 16 + 4 * (lane >> 4) + e;
        const float pre = acc[mi][ni][e];
        const float zg =
            __builtin_amdgcn_rcpf(1.f + __builtin_amdgcn_exp2f(-(pre + bgc) * LOG2E));
        const float hc =
            1.f - 2.f * __builtin_amdgcn_rcpf(
                            1.f + __builtin_amdgcn_exp2f((pre + buc) * (2.f * LOG2E)));
        const float sv = state[(size_t)row * DH + col];
        out[(size_t)row * DH + col] = zg * sv + (sz * (1.f - zg) + sn) * hc;
      }
    }
}

extern "C" void kernel_launch(void* const* d_in, const int* in_sizes, int n_in,
                              void* d_out, int out_size, void* d_ws, size_t ws_size,
                              hipStream_t stream) {
  const float* input = (const float*)d_in[0];
  const float* state = (const float*)d_in[1];
  const float* W1 = (const float*)d_in[2];
  const float* W2 = (const float*)d_in[3];
  const float* U1 = (const float*)d_in[4];
  const float* U2 = (const float*)d_in[5];
  const float* bg = (const float*)d_in[6];
  const float* bu = (const float*)d_in[7];
  const float* zeta = (const float*)d_in[8];
  const float* nu = (const float*)d_in[9];
  float* out = (float*)d_out;

  _Float16* rb6 = (_Float16*)d_ws;                      // 8192*1536*2 = 25.2 MB
  _Float16* rb2 = rb6 + (size_t)8192 * RB6LD;           // 8.4 MB
  _Float16* wb = rb2 + (size_t)8192 * 512;              // 3.67 MB (37.3 MB total)

  fgrnn_prep<<<1792, 256, 0, stream>>>(W1, U1, W2, U2, wb);
  fgrnn_stage1<<<1536, 256, 0, stream>>>(input, state, wb, rb6);
  fgrnn_reduce<<<2048, 256, 0, stream>>>(rb6, rb2);
  fgrnn_stage2<<<2048, 256, 0, stream>>>(rb2, wb, state, bg, bu, zeta, nu, out);
}